// Round 5
// baseline (590.141 us; speedup 1.0000x reference)
//
#include <hip/hip_runtime.h>

// Problem constants
constexpr int BB = 8, NN = 4096, FF = 512, DD = 64, OO = 512;

using short8  = __attribute__((ext_vector_type(8))) short;
using ushort8 = __attribute__((ext_vector_type(8))) unsigned short;
using ushort4v= __attribute__((ext_vector_type(4))) unsigned short;
using f32x4   = __attribute__((ext_vector_type(4))) float;

__device__ __forceinline__ unsigned short f2bf(float f) {
  unsigned int u = __builtin_bit_cast(unsigned int, f);
  return (unsigned short)((u + 0x7FFFu + ((u >> 16) & 1u)) >> 16);
}

__device__ __forceinline__ f32x4 mfma16(short8 a, short8 b, f32x4 c) {
  return __builtin_amdgcn_mfma_f32_16x16x32_bf16(a, b, c, 0, 0, 0);
}

// async global->LDS, 16B per lane; lds base must be wave-uniform (lane l lands at base + l*16)
__device__ __forceinline__ void gl_lds16(const void* g, void* s) {
  __builtin_amdgcn_global_load_lds(
      (const __attribute__((address_space(1))) unsigned int*)g,
      (__attribute__((address_space(3))) unsigned int*)s,
      16, 0, 0);
}

// ---------------- kernel 1: cast x (f32) -> bf16 ----------------
__global__ void cast_x(const float* __restrict__ x, unsigned short* __restrict__ xb) {
  size_t base = ((size_t)blockIdx.x * 256 + threadIdx.x) * 8;
  float4 a = *(const float4*)(x + base);
  float4 b = *(const float4*)(x + base + 4);
  ushort8 o;
  o[0]=f2bf(a.x); o[1]=f2bf(a.y); o[2]=f2bf(a.z); o[3]=f2bf(a.w);
  o[4]=f2bf(b.x); o[5]=f2bf(b.y); o[6]=f2bf(b.z); o[7]=f2bf(b.w);
  *(ushort8*)(xb + base) = o;
}

// ---------------- kernel 2: build Wcat^T [640][512] bf16 + bias[640] ----------------
__global__ void build_w(const float* __restrict__ w1, const float* __restrict__ w2,
                        const float* __restrict__ wgt,
                        const float* __restrict__ b1, const float* __restrict__ b2,
                        unsigned short* __restrict__ Wt, float* __restrict__ bias) {
  int idx = blockIdx.x * 256 + threadIdx.x;   // 640*512 threads
  int j = idx >> 9, kk = idx & 511;
  float v = (j < 64) ? w1[kk * 64 + j]
          : (j < 128) ? w2[kk * 64 + (j - 64)]
                      : wgt[(size_t)kk * 512 + (j - 128)];
  Wt[(size_t)j * 512 + kk] = f2bf(v);
  if (kk == 0) bias[j] = (j < 64) ? b1[j] : (j < 128) ? b2[j - 64] : 0.f;
}

// ---------------- kernel 2b: compact active rows, one block per batch, no atomics ----------------
__global__ void compact_rows(const float* __restrict__ mask, int* __restrict__ cnt,
                             int* __restrict__ ridx) {
  __shared__ int wsum[4];
  __shared__ int base;
  const int b = blockIdx.x;              // 8 blocks
  const int t = threadIdx.x, lane = t & 63, w = t >> 6;
  if (t == 0) base = 0;
  __syncthreads();
  for (int it = 0; it < 16; ++it) {
    int r = it * 256 + t;
    bool act = mask[(b << 12) + r] != 0.f;
    unsigned long long bal = __ballot(act);
    int pre = __popcll(bal & ((1ull << lane) - 1ull));
    if (lane == 0) wsum[w] = __popcll(bal);
    __syncthreads();
    int woff = 0;
    for (int i = 0; i < w; ++i) woff += wsum[i];
    int tot = wsum[0] + wsum[1] + wsum[2] + wsum[3];
    if (act) ridx[(b << 12) + base + woff + pre] = r;
    __syncthreads();
    if (t == 0) base += tot;
    __syncthreads();
  }
  if (t == 0) cnt[b] = base;
}

// ---------------- kernel 2c: zero masked output rows ----------------
__global__ void zero_masked(const float* __restrict__ mask, float* __restrict__ out) {
  int gid = blockIdx.x * 256 + threadIdx.x;  // 32768*128
  int r = gid >> 7, c = (gid & 127) * 4;
  if (mask[r] == 0.f) {
    float4 z = {0.f, 0.f, 0.f, 0.f};
    *(float4*)(out + (size_t)r * 512 + c) = z;
  }
}

// ---------------- kernel 3: fused projection GEMM ----------------
// Y = Xb[32768,512] @ Wcat[512,640]; cols 0..127 -> QK row-major [32768][128],
// cols 128..639 -> supportT [8*512][4096] (transposed store).
__global__ __launch_bounds__(256, 2) void proj_gemm(
    const unsigned short* __restrict__ X, const unsigned short* __restrict__ Wt,
    const float* __restrict__ bias,
    unsigned short* __restrict__ QK, unsigned short* __restrict__ SupT) {
  __shared__ __align__(16) unsigned short Abuf[128 * 64];
  __shared__ __align__(16) unsigned short Bbuf[128 * 64];
  const int t = threadIdx.x, lane = t & 63, w = t >> 6;
  const int nblk = blockIdx.x;           // 0..4
  const int m0 = blockIdx.y * 128, n0 = nblk * 128;
  const int wm = w & 1, wn = w >> 1;

  f32x4 acc[4][4] = {};
  for (int kt = 0; kt < 8; ++kt) {
    for (int i = 0; i < 4; ++i) {
      int c = i * 4 + w;
      int row = c * 8 + (lane >> 3);
      int k0 = (lane & 7) * 8;
      gl_lds16(X + (size_t)(m0 + row) * 512 + kt * 64 + k0, &Abuf[c * 512]);
      gl_lds16(Wt + (size_t)(n0 + row) * 512 + kt * 64 + k0, &Bbuf[c * 512]);
    }
    __syncthreads();
    short8 af[4][2], bfr[4][2];
    for (int mi = 0; mi < 4; ++mi)
      for (int kc = 0; kc < 2; ++kc) {
        int row = wm * 64 + mi * 16 + (lane & 15);
        int d = kc * 32 + (lane >> 4) * 8;
        af[mi][kc] = *(const short8*)&Abuf[row * 64 + d];
      }
    for (int ni = 0; ni < 4; ++ni)
      for (int kc = 0; kc < 2; ++kc) {
        int col = wn * 64 + ni * 16 + (lane & 15);
        int d = kc * 32 + (lane >> 4) * 8;
        bfr[ni][kc] = *(const short8*)&Bbuf[col * 64 + d];
      }
    for (int mi = 0; mi < 4; ++mi)
      for (int ni = 0; ni < 4; ++ni)
        for (int kc = 0; kc < 2; ++kc)
          acc[mi][ni] = mfma16(af[mi][kc], bfr[ni][kc], acc[mi][ni]);
    __syncthreads();
  }
  for (int mi = 0; mi < 4; ++mi)
    for (int ni = 0; ni < 4; ++ni) {
      int col_g = n0 + wn * 64 + ni * 16 + (lane & 15);
      int row0 = m0 + wm * 64 + mi * 16 + ((lane >> 4) * 4);
      float bv = bias[col_g];
      if (nblk == 0) {
        for (int j = 0; j < 4; ++j)
          QK[(size_t)(row0 + j) * 128 + col_g] = f2bf(acc[mi][ni][j] + bv);
      } else {
        int scol = col_g - 128;
        int b = row0 >> 12, rl = row0 & 4095;
        ushort4v pk;
        for (int j = 0; j < 4; ++j) pk[j] = f2bf(acc[mi][ni][j] + bv);
        *(ushort4v*)&SupT[(size_t)(b * 512 + scol) * 4096 + rl] = pk;
      }
    }
}

// ---------------- kernel 4: fused attention, register-direct K/V (no K/V LDS) ----------------
// Block: 64 active rows x 256 cols (colh), 8 waves, BK=32.
// K and V MFMA B-fragments are loaded straight from global (L2-resident, batch
// pinned to one XCD via blockIdx low bits) into loop-carried registers, issued
// one iteration ahead of use. LDS holds only the double-buffered P tile ->
// exactly ONE barrier per K-tile. Softmax denominator accumulated in registers
// (unnormalized exp is safe: |logit| small by construction), divided in epilogue.
__global__ __launch_bounds__(512, 4) void attn_kernel(
    const unsigned short* __restrict__ QK, const unsigned short* __restrict__ SupT,
    const int* __restrict__ cnt, const int* __restrict__ ridx,
    float* __restrict__ out) {
  __shared__ __align__(16) unsigned short Pb[2][64 * 40];   // padded stride 40
  __shared__ float lsh[2][64];
  __shared__ int rsh[64];

  // batch in low bits -> one batch per XCD (L2 affinity)
  const int batch = blockIdx.x & 7;
  const int rest  = blockIdx.x >> 3;       // 0..127
  const int chunk = rest >> 1, colh = rest & 1;
  const int n_act = cnt[batch];
  if (chunk * 64 >= n_act) return;
  const int rem = min(64, n_act - chunk * 64);

  const int t = threadIdx.x, lane = t & 63, w = t >> 6;
  const int keybase = batch << 12;
  const int wm = w >> 2;                 // row half (0,1)
  const int wq = w & 3;
  const int fms = wq >> 1, ks = wq & 1;  // S-phase: 16-row group / 16-key strip
  const int wo = w & 3;                  // PV: 64-col group within 256

  if (t < 64) rsh[t] = ridx[(batch << 12) + chunk * 64 + min(t, rem - 1)];
  __syncthreads();

  short8 aq[2];
  {
    int rl = rsh[wm * 32 + fms * 16 + (lane & 15)];
    for (int kc = 0; kc < 2; ++kc)
      aq[kc] = *(const short8*)&QK[(size_t)(keybase + rl) * 128 + kc * 32 + (lane >> 4) * 8];
  }

  // per-lane fragment base pointers (B-frag layout: col=lane&15, k=(lane>>4)*8)
  const unsigned short* Kp =
      QK + (size_t)(keybase + ks * 16 + (lane & 15)) * 128 + 64 + (lane >> 4) * 8;
  const unsigned short* Vp =
      SupT + (size_t)(batch * 512 + colh * 256 + wo * 64 + (lane & 15)) * 4096 + (lane >> 4) * 8;

  f32x4 acc[2][4] = {};
  float lacc[4] = {0.f, 0.f, 0.f, 0.f};

  // prologue: fragments for tile 0
  short8 kf0 = *(const short8*)(Kp);
  short8 kf1 = *(const short8*)(Kp + 32);
  short8 vf0 = *(const short8*)(Vp);
  short8 vf1 = *(const short8*)(Vp + (size_t)16 * 4096);
  short8 vf2 = *(const short8*)(Vp + (size_t)32 * 4096);
  short8 vf3 = *(const short8*)(Vp + (size_t)48 * 4096);

  const int rl0 = wm * 32 + fms * 16 + (lane >> 4) * 4;
  const int key = ks * 16 + (lane & 15);
  const int prow = wm * 32 + (lane & 15);
  const int pcol = (lane >> 4) * 8;

  for (int kt = 0; kt < 128; ++kt) {
    const int pb = kt & 1;
    // S phase: 16 rows x 16 keys
    f32x4 sa = {0.f, 0.f, 0.f, 0.f};
    __builtin_amdgcn_s_setprio(1);
    sa = mfma16(aq[0], kf0, sa);
    sa = mfma16(aq[1], kf1, sa);
    __builtin_amdgcn_s_setprio(0);

    // prefetch K fragments for next tile (cover: exp + barrier + PV)
    {
      size_t knext = (kt < 127) ? (size_t)(kt + 1) * 32 : 0;
      kf0 = *(const short8*)(Kp + knext * 128);
      kf1 = *(const short8*)(Kp + knext * 128 + 32);
    }

    for (int j = 0; j < 4; ++j) {
      float pv = __expf(sa[j] * 0.125f);
      lacc[j] += pv;
      Pb[pb][(rl0 + j) * 40 + key] = f2bf(pv);
    }
    asm volatile("s_waitcnt lgkmcnt(0)" ::: "memory");
    asm volatile("s_barrier" ::: "memory");

    // PV phase: my 32 rows x 64 cols
    short8 pa0 = *(const short8*)&Pb[pb][prow * 40 + pcol];
    short8 pa1 = *(const short8*)&Pb[pb][(prow + 16) * 40 + pcol];
    __builtin_amdgcn_s_setprio(1);
    acc[0][0] = mfma16(pa0, vf0, acc[0][0]);
    acc[1][0] = mfma16(pa1, vf0, acc[1][0]);
    acc[0][1] = mfma16(pa0, vf1, acc[0][1]);
    acc[1][1] = mfma16(pa1, vf1, acc[1][1]);
    acc[0][2] = mfma16(pa0, vf2, acc[0][2]);
    acc[1][2] = mfma16(pa1, vf2, acc[1][2]);
    acc[0][3] = mfma16(pa0, vf3, acc[0][3]);
    acc[1][3] = mfma16(pa1, vf3, acc[1][3]);
    __builtin_amdgcn_s_setprio(0);

    // load V fragments for next tile (issued after last use; full-iter cover)
    {
      size_t knext = (kt < 127) ? (size_t)(kt + 1) * 32 : 0;
      vf0 = *(const short8*)(Vp + knext);
      vf1 = *(const short8*)(Vp + (size_t)16 * 4096 + knext);
      vf2 = *(const short8*)(Vp + (size_t)32 * 4096 + knext);
      vf3 = *(const short8*)(Vp + (size_t)48 * 4096 + knext);
    }
  }

  // reduce l across the 16 lanes of each key-strip group, then across ks waves
  for (int j = 0; j < 4; ++j) {
    float v = lacc[j];
    v += __shfl_xor(v, 1); v += __shfl_xor(v, 2);
    v += __shfl_xor(v, 4); v += __shfl_xor(v, 8);
    lacc[j] = v;
  }
  if ((lane & 15) == 0) {
    for (int j = 0; j < 4; ++j) lsh[ks][rl0 + j] = lacc[j];
  }
  __syncthreads();

  for (int fm = 0; fm < 2; ++fm)
    for (int ni = 0; ni < 4; ++ni) {
      int colL = wo * 64 + ni * 16 + (lane & 15);
      int sl0 = wm * 32 + fm * 16 + (lane >> 4) * 4;
      for (int j = 0; j < 4; ++j) {
        if (sl0 + j < rem) {
          float linv = 1.f / (lsh[0][sl0 + j] + lsh[1][sl0 + j]);
          int rl = rsh[sl0 + j];
          float av = (fm == 0) ? ((float*)&acc[0][ni])[j] : ((float*)&acc[1][ni])[j];
          out[(size_t)(keybase + rl) * 512 + colh * 256 + colL] = av * linv;
        }
      }
    }
}

extern "C" void kernel_launch(void* const* d_in, const int* in_sizes, int n_in,
                              void* d_out, int out_size, void* d_ws, size_t ws_size,
                              hipStream_t stream) {
  const float* x    = (const float*)d_in[0];
  const float* mask = (const float*)d_in[1];
  const float* w1   = (const float*)d_in[2];
  const float* b1   = (const float*)d_in[3];
  const float* w2   = (const float*)d_in[4];
  const float* b2   = (const float*)d_in[5];
  const float* wgt  = (const float*)d_in[6];
  float* out = (float*)d_out;

  char* ws = (char*)d_ws;
  unsigned short* Xb   = (unsigned short*)(ws);               // 33,554,432 B
  unsigned short* QK   = (unsigned short*)(ws + 33554432);    //  8,388,608 B
  unsigned short* SupT = (unsigned short*)(ws + 41943040);    // 33,554,432 B
  unsigned short* Wt   = (unsigned short*)(ws + 75497472);    //    655,360 B
  float* bias          = (float*)(ws + 76152832);             //      2,560 B
  int*   cnt           = (int*)(ws + 76417536);               //         32 B
  int*   ridx          = (int*)(ws + 76417664);               //    131,072 B

  build_w<<<dim3(1280), dim3(256), 0, stream>>>(w1, w2, wgt, b1, b2, Wt, bias);
  compact_rows<<<dim3(8), dim3(256), 0, stream>>>(mask, cnt, ridx);
  cast_x<<<dim3(8192), dim3(256), 0, stream>>>(x, Xb);
  proj_gemm<<<dim3(5, 256), dim3(256), 0, stream>>>(Xb, Wt, bias, QK, SupT);
  attn_kernel<<<dim3(1024), dim3(512), 0, stream>>>(QK, SupT, cnt, ridx, out);
  zero_masked<<<dim3(16384), dim3(256), 0, stream>>>(mask, out);
}

// Round 6
// 232.968 us; speedup vs baseline: 2.5331x; 2.5331x over previous
//
#include <hip/hip_runtime.h>

// Problem constants
constexpr int BB = 8, NN = 4096, FF = 512, DD = 64, OO = 512;

using short8  = __attribute__((ext_vector_type(8))) short;
using ushort8 = __attribute__((ext_vector_type(8))) unsigned short;
using ushort4v= __attribute__((ext_vector_type(4))) unsigned short;
using f32x4   = __attribute__((ext_vector_type(4))) float;

__device__ __forceinline__ unsigned short f2bf(float f) {
  unsigned int u = __builtin_bit_cast(unsigned int, f);
  return (unsigned short)((u + 0x7FFFu + ((u >> 16) & 1u)) >> 16);
}

__device__ __forceinline__ f32x4 mfma16(short8 a, short8 b, f32x4 c) {
  return __builtin_amdgcn_mfma_f32_16x16x32_bf16(a, b, c, 0, 0, 0);
}

// async global->LDS, 16B per lane; lds base must be wave-uniform (lane l lands at base + l*16)
__device__ __forceinline__ void gl_lds16(const void* g, void* s) {
  __builtin_amdgcn_global_load_lds(
      (const __attribute__((address_space(1))) unsigned int*)g,
      (__attribute__((address_space(3))) unsigned int*)s,
      16, 0, 0);
}

// ---------------- kernel 1: cast x (f32) -> bf16 ----------------
__global__ void cast_x(const float* __restrict__ x, unsigned short* __restrict__ xb) {
  size_t base = ((size_t)blockIdx.x * 256 + threadIdx.x) * 8;
  float4 a = *(const float4*)(x + base);
  float4 b = *(const float4*)(x + base + 4);
  ushort8 o;
  o[0]=f2bf(a.x); o[1]=f2bf(a.y); o[2]=f2bf(a.z); o[3]=f2bf(a.w);
  o[4]=f2bf(b.x); o[5]=f2bf(b.y); o[6]=f2bf(b.z); o[7]=f2bf(b.w);
  *(ushort8*)(xb + base) = o;
}

// ---------------- kernel 2: build Wcat^T [640][512] bf16 + bias[640] ----------------
__global__ void build_w(const float* __restrict__ w1, const float* __restrict__ w2,
                        const float* __restrict__ wgt,
                        const float* __restrict__ b1, const float* __restrict__ b2,
                        unsigned short* __restrict__ Wt, float* __restrict__ bias) {
  int idx = blockIdx.x * 256 + threadIdx.x;   // 640*512 threads
  int j = idx >> 9, kk = idx & 511;
  float v = (j < 64) ? w1[kk * 64 + j]
          : (j < 128) ? w2[kk * 64 + (j - 64)]
                      : wgt[(size_t)kk * 512 + (j - 128)];
  Wt[(size_t)j * 512 + kk] = f2bf(v);
  if (kk == 0) bias[j] = (j < 64) ? b1[j] : (j < 128) ? b2[j - 64] : 0.f;
}

// ---------------- kernel 2b: compact active rows, one block per batch, no atomics ----------------
__global__ void compact_rows(const float* __restrict__ mask, int* __restrict__ cnt,
                             int* __restrict__ ridx) {
  __shared__ int wsum[4];
  __shared__ int base;
  const int b = blockIdx.x;              // 8 blocks
  const int t = threadIdx.x, lane = t & 63, w = t >> 6;
  if (t == 0) base = 0;
  __syncthreads();
  for (int it = 0; it < 16; ++it) {
    int r = it * 256 + t;
    bool act = mask[(b << 12) + r] != 0.f;
    unsigned long long bal = __ballot(act);
    int pre = __popcll(bal & ((1ull << lane) - 1ull));
    if (lane == 0) wsum[w] = __popcll(bal);
    __syncthreads();
    int woff = 0;
    for (int i = 0; i < w; ++i) woff += wsum[i];
    int tot = wsum[0] + wsum[1] + wsum[2] + wsum[3];
    if (act) ridx[(b << 12) + base + woff + pre] = r;
    __syncthreads();
    if (t == 0) base += tot;
    __syncthreads();
  }
  if (t == 0) cnt[b] = base;
}

// ---------------- kernel 2c: zero masked output rows ----------------
__global__ void zero_masked(const float* __restrict__ mask, float* __restrict__ out) {
  int gid = blockIdx.x * 256 + threadIdx.x;  // 32768*128
  int r = gid >> 7, c = (gid & 127) * 4;
  if (mask[r] == 0.f) {
    float4 z = {0.f, 0.f, 0.f, 0.f};
    *(float4*)(out + (size_t)r * 512 + c) = z;
  }
}

// ---------------- kernel 3: fused projection GEMM ----------------
// Y = Xb[32768,512] @ Wcat[512,640]; cols 0..127 -> QK row-major [32768][128],
// cols 128..639 -> supportT [8*512][4096] (transposed store).
__global__ __launch_bounds__(256, 2) void proj_gemm(
    const unsigned short* __restrict__ X, const unsigned short* __restrict__ Wt,
    const float* __restrict__ bias,
    unsigned short* __restrict__ QK, unsigned short* __restrict__ SupT) {
  __shared__ __align__(16) unsigned short Abuf[128 * 64];
  __shared__ __align__(16) unsigned short Bbuf[128 * 64];
  const int t = threadIdx.x, lane = t & 63, w = t >> 6;
  const int nblk = blockIdx.x;           // 0..4
  const int m0 = blockIdx.y * 128, n0 = nblk * 128;
  const int wm = w & 1, wn = w >> 1;

  f32x4 acc[4][4] = {};
  for (int kt = 0; kt < 8; ++kt) {
    for (int i = 0; i < 4; ++i) {
      int c = i * 4 + w;
      int row = c * 8 + (lane >> 3);
      int k0 = (lane & 7) * 8;
      gl_lds16(X + (size_t)(m0 + row) * 512 + kt * 64 + k0, &Abuf[c * 512]);
      gl_lds16(Wt + (size_t)(n0 + row) * 512 + kt * 64 + k0, &Bbuf[c * 512]);
    }
    __syncthreads();
    short8 af[4][2], bfr[4][2];
    for (int mi = 0; mi < 4; ++mi)
      for (int kc = 0; kc < 2; ++kc) {
        int row = wm * 64 + mi * 16 + (lane & 15);
        int d = kc * 32 + (lane >> 4) * 8;
        af[mi][kc] = *(const short8*)&Abuf[row * 64 + d];
      }
    for (int ni = 0; ni < 4; ++ni)
      for (int kc = 0; kc < 2; ++kc) {
        int col = wn * 64 + ni * 16 + (lane & 15);
        int d = kc * 32 + (lane >> 4) * 8;
        bfr[ni][kc] = *(const short8*)&Bbuf[col * 64 + d];
      }
    for (int mi = 0; mi < 4; ++mi)
      for (int ni = 0; ni < 4; ++ni)
        for (int kc = 0; kc < 2; ++kc)
          acc[mi][ni] = mfma16(af[mi][kc], bfr[ni][kc], acc[mi][ni]);
    __syncthreads();
  }
  for (int mi = 0; mi < 4; ++mi)
    for (int ni = 0; ni < 4; ++ni) {
      int col_g = n0 + wn * 64 + ni * 16 + (lane & 15);
      int row0 = m0 + wm * 64 + mi * 16 + ((lane >> 4) * 4);
      float bv = bias[col_g];
      if (nblk == 0) {
        for (int j = 0; j < 4; ++j)
          QK[(size_t)(row0 + j) * 128 + col_g] = f2bf(acc[mi][ni][j] + bv);
      } else {
        int scol = col_g - 128;
        int b = row0 >> 12, rl = row0 & 4095;
        ushort4v pk;
        for (int j = 0; j < 4; ++j) pk[j] = f2bf(acc[mi][ni][j] + bv);
        *(ushort4v*)&SupT[(size_t)(b * 512 + scol) * 4096 + rl] = pk;
      }
    }
}

// ---------------- kernel 4: fused attention, 2 barriers/iter, 3 blocks/CU ----------------
// Block: 64 active rows x 256 cols (colh), 8 waves, BK=32.
// Coalesced gl_lds staging, K/V double-buffered (LDS ~51KB -> 3 blocks/CU).
// stage(kt+1) issued AFTER B1(kt): B1(kt) arrival implies all waves finished
// PV(kt-1), so overwriting buffer (kt+1)&1 is race-free; load latency is
// covered by S+exp+B2+PV of iteration kt. Pb double-buffered -> no post-PV
// barrier. Denominator accumulated in registers (unnormalized exp is safe:
// logits are tiny by construction), divided out in the epilogue.
__global__ __launch_bounds__(512, 6) void attn_kernel(
    const unsigned short* __restrict__ QK, const unsigned short* __restrict__ SupT,
    const int* __restrict__ cnt, const int* __restrict__ ridx,
    float* __restrict__ out) {
  __shared__ __align__(16) unsigned short Kb[2][32 * 64];   // xor-swizzled blocks (8KB)
  __shared__ __align__(16) unsigned short Vt[2][256 * 32];  // [colL][key], xor-swizzled (32KB)
  __shared__ __align__(16) unsigned short Pb[2][64 * 40];   // padded stride 40 (10KB)
  __shared__ float lsh[2][64];
  __shared__ int rsh[64];

  // batch in low bits -> one batch per XCD (L2 affinity)
  const int batch = blockIdx.x & 7;
  const int rest  = blockIdx.x >> 3;       // 0..127
  const int chunk = rest >> 1, colh = rest & 1;
  const int n_act = cnt[batch];
  if (chunk * 64 >= n_act) return;
  const int rem = min(64, n_act - chunk * 64);

  const int t = threadIdx.x, lane = t & 63, w = t >> 6;
  const int keybase = batch << 12;
  const int wm = w >> 2;                 // row half (0,1)
  const int wq = w & 3;
  const int fms = wq >> 1, ks = wq & 1;  // S-phase: 16-row group / 16-key strip
  const int wo = w & 3;                  // PV: 64-col group within 256

  if (t < 64) rsh[t] = ridx[(batch << 12) + chunk * 64 + min(t, rem - 1)];
  __syncthreads();

  short8 aq[2];
  {
    int rl = rsh[wm * 32 + fms * 16 + (lane & 15)];
    for (int kc = 0; kc < 2; ++kc)
      aq[kc] = *(const short8*)&QK[(size_t)(keybase + rl) * 128 + kc * 32 + (lane >> 4) * 8];
  }

  f32x4 acc[2][4] = {};
  float lacc[4] = {0.f, 0.f, 0.f, 0.f};
  const int rl0 = wm * 32 + fms * 16 + (lane >> 4) * 4;

  auto stage = [&](int p, int key0) {
    if (w < 4) {  // K tile: 32 keys x 64 d (1 instr, waves 0-3)
      int key = w * 8 + (lane >> 3);
      int q = lane & 7;
      int d0 = (q ^ (key & 7)) * 8;
      gl_lds16(QK + (size_t)(keybase + key0 + key) * 128 + 64 + d0, &Kb[p][w * 512]);
    }
    for (int i = 0; i < 2; ++i) {  // Vt tile: 256 cols x 32 keys (2 instr/wave)
      int c = i * 8 + w;                     // 0..15 local col-block
      int colL = c * 16 + (lane >> 2);       // local col 0..255
      int q = lane & 3;
      int k0 = (q ^ ((colL >> 1) & 3)) * 8;
      gl_lds16(SupT + (size_t)(batch * 512 + colh * 256 + colL) * 4096 + key0 + k0,
               &Vt[p][c * 512]);
    }
  };

  stage(0, 0);
  for (int kt = 0; kt < 128; ++kt) {
    const int p = kt & 1;
    // B1: tile kt arrived (only our own stage(kt) loads are outstanding)
    asm volatile("s_waitcnt vmcnt(0)" ::: "memory");
    asm volatile("s_barrier" ::: "memory");

    // prefetch tile kt+1 into buffer p^1 (race-free: all waves passed B1 =>
    // all finished PV(kt-1) which read buffer p^1)
    if (kt < 127) stage(p ^ 1, (kt + 1) * 32);

    // S phase: this wave's 16 rows x 16 keys, unnormalized exp, l-accumulate
    {
      f32x4 sa = {0.f, 0.f, 0.f, 0.f};
      int key = ks * 16 + (lane & 15);
      __builtin_amdgcn_s_setprio(1);
      for (int kc = 0; kc < 2; ++kc) {
        int dblk = kc * 4 + (lane >> 4);
        int blk = dblk ^ (key & 7);
        short8 bk = *(const short8*)&Kb[p][key * 64 + blk * 8];
        sa = mfma16(aq[kc], bk, sa);
      }
      __builtin_amdgcn_s_setprio(0);
      for (int j = 0; j < 4; ++j) {
        float pv = __expf(sa[j] * 0.125f);
        lacc[j] += pv;
        Pb[p][(rl0 + j) * 40 + key] = f2bf(pv);
      }
    }
    asm volatile("s_waitcnt lgkmcnt(0)" ::: "memory");
    asm volatile("s_barrier" ::: "memory");            // B2: P handoff

    // PV phase: 64 rows x 256 cols
    short8 pa[2];
    for (int fm = 0; fm < 2; ++fm) {
      int row = wm * 32 + fm * 16 + (lane & 15);
      pa[fm] = *(const short8*)&Pb[p][row * 40 + (lane >> 4) * 8];
    }
    __builtin_amdgcn_s_setprio(1);
    for (int ni = 0; ni < 4; ++ni) {
      int colL = wo * 64 + ni * 16 + (lane & 15);
      int blk = (lane >> 4) ^ ((colL >> 1) & 3);
      short8 vb = *(const short8*)&Vt[p][colL * 32 + blk * 8];
      acc[0][ni] = mfma16(pa[0], vb, acc[0][ni]);
      acc[1][ni] = mfma16(pa[1], vb, acc[1][ni]);
    }
    __builtin_amdgcn_s_setprio(0);
  }

  // reduce l across the 16 lanes of each key-strip group, then across ks waves
  for (int j = 0; j < 4; ++j) {
    float v = lacc[j];
    v += __shfl_xor(v, 1); v += __shfl_xor(v, 2);
    v += __shfl_xor(v, 4); v += __shfl_xor(v, 8);
    lacc[j] = v;
  }
  if ((lane & 15) == 0) {
    for (int j = 0; j < 4; ++j) lsh[ks][rl0 + j] = lacc[j];
  }
  __syncthreads();

  for (int fm = 0; fm < 2; ++fm)
    for (int ni = 0; ni < 4; ++ni) {
      int colL = wo * 64 + ni * 16 + (lane & 15);
      int sl0 = wm * 32 + fm * 16 + (lane >> 4) * 4;
      for (int j = 0; j < 4; ++j) {
        if (sl0 + j < rem) {
          float linv = 1.f / (lsh[0][sl0 + j] + lsh[1][sl0 + j]);
          int rl = rsh[sl0 + j];
          float av = ((float*)&acc[fm][ni])[j];
          out[(size_t)(keybase + rl) * 512 + colh * 256 + colL] = av * linv;
        }
      }
    }
}

extern "C" void kernel_launch(void* const* d_in, const int* in_sizes, int n_in,
                              void* d_out, int out_size, void* d_ws, size_t ws_size,
                              hipStream_t stream) {
  const float* x    = (const float*)d_in[0];
  const float* mask = (const float*)d_in[1];
  const float* w1   = (const float*)d_in[2];
  const float* b1   = (const float*)d_in[3];
  const float* w2   = (const float*)d_in[4];
  const float* b2   = (const float*)d_in[5];
  const float* wgt  = (const float*)d_in[6];
  float* out = (float*)d_out;

  char* ws = (char*)d_ws;
  unsigned short* Xb   = (unsigned short*)(ws);               // 33,554,432 B
  unsigned short* QK   = (unsigned short*)(ws + 33554432);    //  8,388,608 B
  unsigned short* SupT = (unsigned short*)(ws + 41943040);    // 33,554,432 B
  unsigned short* Wt   = (unsigned short*)(ws + 75497472);    //    655,360 B
  float* bias          = (float*)(ws + 76152832);             //      2,560 B
  int*   cnt           = (int*)(ws + 76417536);               //         32 B
  int*   ridx          = (int*)(ws + 76417664);               //    131,072 B

  build_w<<<dim3(1280), dim3(256), 0, stream>>>(w1, w2, wgt, b1, b2, Wt, bias);
  compact_rows<<<dim3(8), dim3(256), 0, stream>>>(mask, cnt, ridx);
  cast_x<<<dim3(8192), dim3(256), 0, stream>>>(x, Xb);
  proj_gemm<<<dim3(5, 256), dim3(256), 0, stream>>>(Xb, Wt, bias, QK, SupT);
  attn_kernel<<<dim3(1024), dim3(512), 0, stream>>>(QK, SupT, cnt, ridx, out);
  zero_masked<<<dim3(16384), dim3(256), 0, stream>>>(mask, out);
}